// Round 6
// baseline (1030.392 us; speedup 1.0000x reference)
//
#include <hip/hip_runtime.h>

#define NSTEPS 730
#define NGRID  10000
#define LENF   15
#define NEARZERO 1e-5f
#define PF 5      // prefetch ring depth; divides LENF so i%PF is static in the 15-unroll
#define C  4      // cells per thread (ILP chains); NGRID = C * NT exactly
#define NT 2500   // threads total

// fast pow(x, e) for x > 0 via v_log_f32 / v_exp_f32 (both base-2)
__device__ __forceinline__ float fast_pow(float x, float e) {
    return __builtin_amdgcn_exp2f(e * __builtin_amdgcn_logf(x));
}

struct F3 { float p, t, e; };  // one (prcp, tmean, pet) sample; 12B

struct HbvParams {
    float TT, CFMAX, CFRxCFMAX, CWH;
    float FC, invFC, BETA, invLPFC, BETAET, C_;
    float PERC, K0, K1, K2, UZL;
};

struct HbvState {
    float snow, melt, sm, suz, slz;
};

// One HBV time step. Returns q = q0+q1+q2.
__device__ __forceinline__ float hbv_step(float p, float tmn, float pet,
                                          HbvState& s, const HbvParams& P) {
    // snow routine
    float rain     = (tmn >= P.TT) ? p : 0.0f;
    float snowfall = p - rain;
    s.snow += snowfall;
    float m = fminf(fmaxf(P.CFMAX * (tmn - P.TT), 0.0f), s.snow);
    s.melt += m; s.snow -= m;
    float refr = fminf(fmaxf(P.CFRxCFMAX * (P.TT - tmn), 0.0f), s.melt);
    s.snow += refr; s.melt -= refr;
    float tosoil = fmaxf(s.melt - P.CWH * s.snow, 0.0f);
    s.melt -= tosoil;

    // soil routine
    float soil_wet = fminf(fast_pow(s.sm * P.invFC, P.BETA), 1.0f);
    float rt_in    = rain + tosoil;
    float recharge = rt_in * soil_wet;
    s.sm += rt_in - recharge;
    float excess = fmaxf(s.sm - P.FC, 0.0f);
    s.sm -= excess;
    float evapfac = fminf(fast_pow(s.sm * P.invLPFC, P.BETAET), 1.0f);
    float etact   = fminf(s.sm, pet * evapfac);
    s.sm = fmaxf(s.sm - etact, NEARZERO);
    float capillary = fminf(s.slz, P.C_ * s.slz * (1.0f - fminf(s.sm * P.invFC, 1.0f)));
    s.sm  = fmaxf(s.sm + capillary, NEARZERO);
    s.slz = fmaxf(s.slz - capillary, NEARZERO);

    // runoff
    s.suz += recharge + excess;
    float percact = fminf(s.suz, P.PERC);
    s.suz -= percact;
    float q0 = P.K0 * fmaxf(s.suz - P.UZL, 0.0f);
    s.suz -= q0;
    float q1 = P.K1 * s.suz;
    s.suz -= q1;
    s.slz += percact;
    float q2 = P.K2 * s.slz;
    s.slz -= q2;
    return q0 + q1 + q2;
}

// Fused HBV chain + in-register 15-tap gamma routing, C=4 independent cell
// chains per thread for ILP (fills the ~8.5cy/instr dependency-latency gaps
// of a lone wave on its SIMD). 1 wave per SIMD by construction (40 blocks on
// 256 CUs); __launch_bounds__(64,1) gives the allocator the full VGPR budget.
__global__ __launch_bounds__(64, 1) void hbv_fused(const float* __restrict__ xp,
                                                   const float* __restrict__ ps,
                                                   float* __restrict__ out) {
    int tid = blockIdx.x * 64 + threadIdx.x;
    if (tid >= NT) return;

    int g[C];
#pragma unroll
    for (int c = 0; c < C; ++c) g[c] = tid + c * NT;

    // --- parameters + routing weights per cell ---
    HbvParams P[C];
    float w[C][LENF];
#pragma unroll
    for (int c = 0; c < C; ++c) {
        const int pb = g[c] * 16;
        P[c].BETA   = ps[pb + 0]  * 5.0f   + 1.0f;
        P[c].FC     = ps[pb + 1]  * 950.0f + 50.0f;
        P[c].K0     = ps[pb + 2]  * 0.85f  + 0.05f;
        P[c].K1     = ps[pb + 3]  * 0.49f  + 0.01f;
        P[c].K2     = ps[pb + 4]  * 0.199f + 0.001f;
        float LP    = ps[pb + 5]  * 0.8f   + 0.2f;
        P[c].PERC   = ps[pb + 6]  * 10.0f;
        P[c].UZL    = ps[pb + 7]  * 100.0f;
        P[c].TT     = ps[pb + 8]  * 5.0f   - 2.5f;
        float CFMAX = ps[pb + 9]  * 9.5f   + 0.5f;
        P[c].CFMAX  = CFMAX;
        P[c].CFRxCFMAX = (ps[pb + 10] * 0.1f) * CFMAX;
        P[c].CWH    = ps[pb + 11] * 0.2f;
        P[c].BETAET = ps[pb + 12] * 4.7f   + 0.3f;
        P[c].C_     = ps[pb + 13];
        P[c].invFC   = 1.0f / P[c].FC;
        P[c].invLPFC = 1.0f / (LP * P[c].FC);

        // routing weights: -lgamma(aa)-aa*log(theta) are k-independent and
        // cancel under normalization. lw2 = (aa-1)*log2(tg) - (tg/theta)*log2e
        const float LOG2E = 1.4426950408889634f;
        float aa    = fmaxf(ps[pb + 14] * 2.9f, 0.0f) + 0.1f;
        float theta = fmaxf(ps[pb + 15] * 6.5f, 0.0f) + 0.5f;
        float sc    = LOG2E / theta;
        float am1   = aa - 1.0f;
        float wsum  = 0.0f;
#pragma unroll
        for (int k = 0; k < LENF; ++k) {
            float tg = (float)k + 0.5f;
            w[c][k] = __builtin_amdgcn_exp2f(am1 * __builtin_amdgcn_logf(tg) - tg * sc);
            wsum += w[c][k];
        }
        float inv = 1.0f / wsum;
#pragma unroll
        for (int k = 0; k < LENF; ++k) w[c][k] *= inv;
    }

    // --- state + circular q-history (zero == reference zero padding) ---
    HbvState st[C];
    float qh[C][LENF];
#pragma unroll
    for (int c = 0; c < C; ++c) {
        st[c] = HbvState{NEARZERO, NEARZERO, NEARZERO, NEARZERO, NEARZERO};
#pragma unroll
        for (int k = 0; k < LENF; ++k) qh[c][k] = 0.0f;
    }

    // --- depth-PF vectorized prefetch ring per cell ---
    const F3* __restrict__ xv = (const F3*)xp;
    F3 pf[C][PF];
#pragma unroll
    for (int i = 0; i < PF; ++i)
#pragma unroll
        for (int c = 0; c < C; ++c)
            pf[c][i] = xv[(size_t)i * NGRID + g[c]];

    // main loop: 48 blocks of 15 steps (t = 0..719); t+PF <= 724 < 730, no guard
    for (int tb = 0; tb < 720; tb += LENF) {
#pragma unroll
        for (int i = 0; i < LENF; ++i) {
            int t = tb + i;
#pragma unroll
            for (int c = 0; c < C; ++c) {
                F3 cur = pf[c][i % PF];
                pf[c][i % PF] = xv[(size_t)(t + PF) * NGRID + g[c]];

                float q = hbv_step(cur.p, cur.t, cur.e, st[c], P[c]);
                qh[c][i] = q;                  // phase = i (tb % 15 == 0)
                float acc = 0.0f;
#pragma unroll
                for (int k = 0; k < LENF; ++k)
                    acc = fmaf(w[c][k], qh[c][(i - k + LENF) % LENF], acc);
                out[t * NGRID + g[c]] = acc;
            }
        }
    }

    // tail: t = 720..729 (phase 0..9); prefetch only while t+PF < 730
#pragma unroll
    for (int i = 0; i < 10; ++i) {
        int t = 720 + i;
#pragma unroll
        for (int c = 0; c < C; ++c) {
            F3 cur = pf[c][i % PF];
            if (i < PF)
                pf[c][i % PF] = xv[(size_t)(t + PF) * NGRID + g[c]];

            float q = hbv_step(cur.p, cur.t, cur.e, st[c], P[c]);
            qh[c][i] = q;
            float acc = 0.0f;
#pragma unroll
            for (int k = 0; k < LENF; ++k)
                acc = fmaf(w[c][k], qh[c][(i - k + LENF) % LENF], acc);
            out[t * NGRID + g[c]] = acc;
        }
    }
}

extern "C" void kernel_launch(void* const* d_in, const int* in_sizes, int n_in,
                              void* d_out, int out_size, void* d_ws, size_t ws_size,
                              hipStream_t stream) {
    const float* x_phy      = (const float*)d_in[0]; // f32 (730,10000,3)
    const float* phy_static = (const float*)d_in[1]; // f32 (10000,16)
    float* out = (float*)d_out;                      // f32 (730,10000)

    hbv_fused<<<(NT + 63) / 64, 64, 0, stream>>>(x_phy, phy_static, out);
}

// Round 7
// 254.596 us; speedup vs baseline: 4.0472x; 4.0472x over previous
//
#include <hip/hip_runtime.h>

#define NSTEPS 730
#define NGRID  10000
#define LENF   15
#define NEARZERO 1e-5f
#define PF 5      // prefetch depth; 730 = 5*146 exactly -> no tail, static ring slots

// fast pow(x, e) for x > 0 via v_log_f32 / v_exp_f32 (both base-2)
__device__ __forceinline__ float fast_pow(float x, float e) {
    return __builtin_amdgcn_exp2f(e * __builtin_amdgcn_logf(x));
}

struct F3 { float p, t, e; };  // one (prcp, tmean, pet) sample; 12B

// Fused HBV chain + transposed-FIR (systolic) 15-tap gamma routing.
// One thread per cell (157 waves on 1024 SIMDs -> every wave has its own SIMD;
// wall time = 730 * per-step serial time, so the ONLY lever is shortening the
// single-step dependency walk). Rolled 146-iter loop, unroll 5 (ring slots
// static), ~2.8 KB body -> I-cache resident.
__global__ __launch_bounds__(64, 1) void hbv_fused(const float* __restrict__ xp,
                                                   const float* __restrict__ ps,
                                                   float* __restrict__ out) {
    int g = blockIdx.x * 64 + threadIdx.x;
    if (g >= NGRID) return;

    // --- parameters (raw in [0,1], scaled per PARAM_BOUNDS) ---
    const int pb = g * 16;
    const float BETA   = ps[pb + 0]  * 5.0f   + 1.0f;
    const float FC     = ps[pb + 1]  * 950.0f + 50.0f;
    const float K0     = ps[pb + 2]  * 0.85f  + 0.05f;
    const float K1     = ps[pb + 3]  * 0.49f  + 0.01f;
    const float K2     = ps[pb + 4]  * 0.199f + 0.001f;
    const float LP     = ps[pb + 5]  * 0.8f   + 0.2f;
    const float PERC   = ps[pb + 6]  * 10.0f;
    const float UZL    = ps[pb + 7]  * 100.0f;
    const float TT     = ps[pb + 8]  * 5.0f   - 2.5f;
    const float CFMAX  = ps[pb + 9]  * 9.5f   + 0.5f;
    const float CFRxCFMAX = (ps[pb + 10] * 0.1f) * CFMAX;
    const float CWH    = ps[pb + 11] * 0.2f;
    const float BETAET = ps[pb + 12] * 4.7f   + 0.3f;
    const float C_     = ps[pb + 13];
    const float invFC   = 1.0f / FC;
    const float invLPFC = 1.0f / (LP * FC);

    // --- routing weights. -lgamma(aa)-aa*log(theta) are k-independent and
    // cancel under normalization. lw2 = (aa-1)*log2(tg) - (tg/theta)*log2(e)
    float w[LENF];
    {
        const float LOG2E = 1.4426950408889634f;
        float aa    = fmaxf(ps[pb + 14] * 2.9f, 0.0f) + 0.1f;
        float theta = fmaxf(ps[pb + 15] * 6.5f, 0.0f) + 0.5f;
        float sc    = LOG2E / theta;
        float am1   = aa - 1.0f;
        float wsum  = 0.0f;
#pragma unroll
        for (int k = 0; k < LENF; ++k) {
            float tg = (float)k + 0.5f;
            w[k] = __builtin_amdgcn_exp2f(am1 * __builtin_amdgcn_logf(tg) - tg * sc);
            wsum += w[k];
        }
        float inv = 1.0f / wsum;
#pragma unroll
        for (int k = 0; k < LENF; ++k) w[k] *= inv;
    }

    // --- state ---
    float snow = NEARZERO, melt = NEARZERO, sm = NEARZERO, suz = NEARZERO, slz = NEARZERO;

    // transposed-FIR state: r[j] = pending contribution to out[t+j]
    float r[LENF - 1];
#pragma unroll
    for (int j = 0; j < LENF - 1; ++j) r[j] = 0.0f;

    // --- depth-PF raw-input prefetch ring (one dwordx3 per step) ---
    const F3* __restrict__ xv = (const F3*)xp;
    F3 ring[PF];
#pragma unroll
    for (int i = 0; i < PF; ++i) ring[i] = xv[(size_t)i * NGRID + g];

    for (int it = 0; it < NSTEPS / PF; ++it) {
        int tb = it * PF;
#pragma unroll
        for (int i = 0; i < PF; ++i) {
            int t = tb + i;
            F3 cur = ring[i];
            int row = t + PF; row = (row > NSTEPS - 1) ? (NSTEPS - 1) : row;
            ring[i] = xv[(size_t)row * NGRID + g];

            // input prep (off the loop-carried chain; operands loaded 5 steps ago)
            float rain     = (cur.t >= TT) ? cur.p : 0.0f;
            float snowfall = cur.p - rain;
            float mm       = fmaxf(CFMAX * (cur.t - TT), 0.0f);       // melt cap
            float rr       = fmaxf(CFRxCFMAX * (TT - cur.t), 0.0f);   // refreeze cap

            // snow routine (short chain, parallel to sm's pow)
            snow += snowfall;
            float m = fminf(mm, snow);
            melt += m; snow -= m;
            float refr = fminf(rr, melt);
            snow += refr; melt -= refr;
            float tosoil = fmaxf(fmaf(-CWH, snow, melt), 0.0f);
            melt -= tosoil;

            // soil routine (the binding loop-carried cycle)
            float sw    = fminf(fast_pow(sm * invFC, BETA), 1.0f);
            float rt_in = rain + tosoil;
            float recharge = rt_in * sw;                 // off-chain (feeds suz)
            float sm1   = fmaf(rt_in, 1.0f - sw, sm);
            float excess = fmaxf(sm1 - FC, 0.0f);        // off-chain (feeds suz)
            float sm2   = fminf(sm1, FC);                // == sm1 - excess
            float ef    = fminf(fast_pow(sm2 * invLPFC, BETAET), 1.0f);
            float pe    = cur.e * ef;
            float sm3   = fmaxf(sm2 - pe, NEARZERO);     // == max(sm2-min(sm2,pe),NZ)
            float d     = 1.0f - fminf(sm3 * invFC, 1.0f);
            float cap   = fminf(slz, (C_ * slz) * d);
            sm = sm3 + cap;                              // cap>=0, sm3>=NZ -> max redundant
            float slz1 = fmaxf(slz - cap, NEARZERO);

            // runoff (short chains off recharge/excess/percact)
            float suz1    = suz + recharge + excess;
            float percact = fminf(suz1, PERC);
            float suz2    = suz1 - percact;
            float q0      = K0 * fmaxf(suz2 - UZL, 0.0f);
            float suz3    = suz2 - q0;
            float q1      = K1 * suz3;
            suz = suz3 - q1;
            float slz2 = slz1 + percact;
            float q2   = K2 * slz2;
            slz = slz2 - q2;
            float q = (q0 + q1) + q2;

            // transposed FIR: 16 independent ops, no serial accumulator
            out[t * NGRID + g] = fmaf(w[0], q, r[0]);
#pragma unroll
            for (int j = 0; j < LENF - 2; ++j)
                r[j] = fmaf(w[j + 1], q, r[j + 1]);
            r[LENF - 2] = w[LENF - 1] * q;
        }
    }
}

extern "C" void kernel_launch(void* const* d_in, const int* in_sizes, int n_in,
                              void* d_out, int out_size, void* d_ws, size_t ws_size,
                              hipStream_t stream) {
    const float* x_phy      = (const float*)d_in[0]; // f32 (730,10000,3)
    const float* phy_static = (const float*)d_in[1]; // f32 (10000,16)
    float* out = (float*)d_out;                      // f32 (730,10000)

    hbv_fused<<<(NGRID + 63) / 64, 64, 0, stream>>>(x_phy, phy_static, out);
}

// Round 8
// 207.122 us; speedup vs baseline: 4.9748x; 1.2292x over previous
//
#include <hip/hip_runtime.h>

#define NSTEPS 730
#define NGRID  10000
#define LENF   15
#define NEARZERO 1e-5f
#define KB 10           // steps per pipeline block
#define NBLK 73         // 730 = 73 * 10
#define NROUND (NBLK + 2)

struct F3 { float p, t, e; };  // (prcp, tmean, pet), 12B

// 3-wave software pipeline, one workgroup = 192 threads = 3 waves handling 64
// cells. Wave A: input load + snowpack chain -> LDS. Wave B: soil/runoff chain
// (the irreducible serial core: 4 transcendentals on the loop-carried cycle)
// -> LDS. Wave C: transposed-FIR gamma routing + stores. Double-buffered LDS
// blocks of KB steps, skew A=n / B=n-1 / C=n-2, one barrier per round.
__global__ __launch_bounds__(192, 1) void hbv_pipe(const float* __restrict__ xp,
                                                   const float* __restrict__ ps,
                                                   float* __restrict__ out) {
    __shared__ float rt_buf[2][KB][64];   // A -> B : rain + tosoil
    __shared__ float pet_buf[2][KB][64];  // A -> B : pet passthrough
    __shared__ float q_buf[2][KB][64];    // B -> C : q

    const int lane = threadIdx.x & 63;
    const int wid  = threadIdx.x >> 6;
    int g = blockIdx.x * 64 + lane;
    g = (g < NGRID) ? g : (NGRID - 1);    // clamp: dup work on last wg, benign
    const int pb = g * 16;
    const F3* __restrict__ xv = (const F3*)xp;

    // ---- role A state ----
    float aTT = 0, aCFMAX = 0, aCFRxCFMAX = 0, aCWH = 0;
    float snow = NEARZERO, melt = NEARZERO;
    // ---- role B state ----
    float bFC = 0, bBETA = 0, bB1 = 0, bBETAET = 0, bB2 = 0, bInvFC = 0,
          bC = 0, bPERC = 0, bK0 = 0, bK1 = 0, bK2 = 0, bUZL = 0;
    float sm = NEARZERO, suz = NEARZERO, slz = NEARZERO;
    // ---- role C state ----
    float w[LENF];
    float r[LENF - 1];

    if (wid == 0) {
        aTT        = ps[pb + 8]  * 5.0f - 2.5f;
        aCFMAX     = ps[pb + 9]  * 9.5f + 0.5f;
        aCFRxCFMAX = (ps[pb + 10] * 0.1f) * aCFMAX;
        aCWH       = ps[pb + 11] * 0.2f;
    } else if (wid == 1) {
        bFC     = ps[pb + 1]  * 950.0f + 50.0f;
        bBETA   = ps[pb + 0]  * 5.0f   + 1.0f;
        float LP = ps[pb + 5] * 0.8f   + 0.2f;
        bBETAET = ps[pb + 12] * 4.7f   + 0.3f;
        bInvFC  = 1.0f / bFC;
        // fold the argument scaling into the log: log2(x/FC)=log2(x)-log2(FC)
        bB1 = -bBETA   * __builtin_amdgcn_logf(bFC);
        bB2 = -bBETAET * __builtin_amdgcn_logf(LP * bFC);
        bC   = ps[pb + 13];
        bPERC = ps[pb + 6] * 10.0f;
        bK0  = ps[pb + 2] * 0.85f  + 0.05f;
        bK1  = ps[pb + 3] * 0.49f  + 0.01f;
        bK2  = ps[pb + 4] * 0.199f + 0.001f;
        bUZL = ps[pb + 7] * 100.0f;
    } else {
        // routing weights; -lgamma(aa)-aa*log(theta) cancel under normalization
        const float LOG2E = 1.4426950408889634f;
        float aa    = fmaxf(ps[pb + 14] * 2.9f, 0.0f) + 0.1f;
        float theta = fmaxf(ps[pb + 15] * 6.5f, 0.0f) + 0.5f;
        float sc = LOG2E / theta, am1 = aa - 1.0f, wsum = 0.0f;
#pragma unroll
        for (int k = 0; k < LENF; ++k) {
            float tg = (float)k + 0.5f;
            w[k] = __builtin_amdgcn_exp2f(am1 * __builtin_amdgcn_logf(tg) - tg * sc);
            wsum += w[k];
        }
        float inv = 1.0f / wsum;
#pragma unroll
        for (int k = 0; k < LENF; ++k) w[k] *= inv;
#pragma unroll
        for (int j = 0; j < LENF - 1; ++j) r[j] = 0.0f;
    }

    for (int n = 0; n < NROUND; ++n) {
        if (wid == 0) {
            if (n < NBLK) {
                F3 in[KB];
#pragma unroll
                for (int i = 0; i < KB; ++i)
                    in[i] = xv[(size_t)(n * KB + i) * NGRID + g];
                float (*rtb)[64] = rt_buf[n & 1];
                float (*peb)[64] = pet_buf[n & 1];
#pragma unroll
                for (int i = 0; i < KB; ++i) {
                    float p = in[i].p, tm = in[i].t;
                    float rain = (tm >= aTT) ? p : 0.0f;
                    float mm = fmaxf(aCFMAX * (tm - aTT), 0.0f);
                    float rr = fmaxf(aCFRxCFMAX * (aTT - tm), 0.0f);
                    snow += p - rain;
                    float m = fminf(mm, snow);
                    melt += m; snow -= m;
                    float refr = fminf(rr, melt);
                    snow += refr; melt -= refr;
                    float tosoil = fmaxf(fmaf(-aCWH, snow, melt), 0.0f);
                    melt -= tosoil;
                    rtb[i][lane] = rain + tosoil;
                    peb[i][lane] = in[i].e;
                }
            }
        } else if (wid == 1) {
            if (n >= 1 && n <= NBLK) {
                int buf = (n - 1) & 1;
                float rt[KB], pe[KB];
#pragma unroll
                for (int i = 0; i < KB; ++i) {
                    rt[i] = rt_buf[buf][i][lane];
                    pe[i] = pet_buf[buf][i][lane];
                }
#pragma unroll
                for (int i = 0; i < KB; ++i) {
                    float l1  = __builtin_amdgcn_logf(sm);
                    float sw  = fminf(__builtin_amdgcn_exp2f(fmaf(bBETA, l1, bB1)), 1.0f);
                    float smp = sm + rt[i];
                    float sm1 = fmaf(-rt[i], sw, smp);
                    float rch = rt[i] * sw;
                    float sm2 = fminf(sm1, bFC);
                    float exc = fmaxf(sm1 - bFC, 0.0f);
                    float l2  = __builtin_amdgcn_logf(sm2);
                    float ef  = fminf(__builtin_amdgcn_exp2f(fmaf(bBETAET, l2, bB2)), 1.0f);
                    float sm3 = fmaxf(fmaf(-pe[i], ef, sm2), NEARZERO);
                    float d   = fmaxf(fmaf(-bInvFC, sm3, 1.0f), 0.0f);
                    float cz  = bC * slz;
                    float cap = fminf(slz, cz * d);
                    sm = sm3 + cap;
                    float slz1 = fmaxf(slz - cap, NEARZERO);
                    float su1 = suz + rch + exc;
                    float pa  = fminf(su1, bPERC);
                    float su2 = su1 - pa;
                    float q0  = bK0 * fmaxf(su2 - bUZL, 0.0f);
                    float su3 = su2 - q0;
                    float q1  = bK1 * su3;
                    suz = su3 - q1;
                    float sl2 = slz1 + pa;
                    float q2  = bK2 * sl2;
                    slz = sl2 - q2;
                    q_buf[buf][i][lane] = (q0 + q1) + q2;
                }
            }
        } else {
            if (n >= 2) {
                int m = n - 2, buf = m & 1;
                float qv[KB];
#pragma unroll
                for (int i = 0; i < KB; ++i) qv[i] = q_buf[buf][i][lane];
#pragma unroll
                for (int i = 0; i < KB; ++i) {
                    float q = qv[i];
                    out[(size_t)(m * KB + i) * NGRID + g] = fmaf(w[0], q, r[0]);
#pragma unroll
                    for (int j = 0; j < LENF - 2; ++j)
                        r[j] = fmaf(w[j + 1], q, r[j + 1]);
                    r[LENF - 2] = w[LENF - 1] * q;
                }
            }
        }
        __syncthreads();
    }
}

extern "C" void kernel_launch(void* const* d_in, const int* in_sizes, int n_in,
                              void* d_out, int out_size, void* d_ws, size_t ws_size,
                              hipStream_t stream) {
    const float* x_phy      = (const float*)d_in[0]; // f32 (730,10000,3)
    const float* phy_static = (const float*)d_in[1]; // f32 (10000,16)
    float* out = (float*)d_out;                      // f32 (730,10000)

    int nwg = (NGRID + 63) / 64;  // 157 workgroups x 192 threads
    hbv_pipe<<<nwg, 192, 0, stream>>>(x_phy, phy_static, out);
}